// Round 12
// baseline (304.550 us; speedup 1.0000x reference)
//
#include <hip/hip_runtime.h>

#define EPSF 1e-6f

typedef _Float16 half8 __attribute__((ext_vector_type(8)));
typedef float f32x4 __attribute__((ext_vector_type(4)));

constexpr int B = 128, L = 512, S = 512, C = 64;
constexpr int TILE_R = 64;            // rows per pass-1 block
constexpr int TILES  = L / TILE_R;    // 8
constexpr int CHUNK  = 64;            // cols per k-chunk
constexpr int NCHUNK = S / CHUNK;     // 8
constexpr int HALVES = 2;             // S-split: each block does NCHUNK/HALVES chunks
constexpr int CPB    = NCHUNK / HALVES;   // 4 chunks per block

// workspace float offsets (row stats are per-half partials)
constexpr size_t WS_COLMAX = 0;
constexpr size_t WS_COLSUM = WS_COLMAX + (size_t)B * TILES * S;
constexpr size_t WS_COLSSQ = WS_COLSUM + (size_t)B * TILES * S;
constexpr size_t WS_COLP1  = WS_COLSSQ + (size_t)B * TILES * S;
constexpr size_t WS_ROWMAX = WS_COLP1  + (size_t)B * TILES * S;
constexpr size_t WS_ROWSUM = WS_ROWMAX + (size_t)B * L * HALVES;
constexpr size_t WS_ROWSSQ = WS_ROWSUM + (size_t)B * L * HALVES;
constexpr size_t WS_ROWP2  = WS_ROWSSQ + (size_t)B * L * HALVES;
constexpr size_t WS_NEGS   = WS_ROWP2  + (size_t)B * L * HALVES;
constexpr size_t WS_NEGC   = WS_NEGS   + (size_t)B * TILES * HALVES;

// Load a thread's 16 consecutive floats of a 64x64 tile: row = t>>2, c0 = (t&3)*16.
__device__ inline void loadTile(const float* __restrict__ g, float4 v[4], int t)
{
    const float* src = g + (t >> 2) * 64 + (t & 3) * 16;
    v[0] = *(const float4*)(src);
    v[1] = *(const float4*)(src + 4);
    v[2] = *(const float4*)(src + 8);
    v[3] = *(const float4*)(src + 12);
}

// Write regs into frag-swizzled fp16 hi/lo LDS:
// arr[(row>>4)*2 + (c>>5)][(((c>>3)&3)<<4) + (row&15)][c&7] -> fragment read is
// one lane-linear ds_read_b128. No __restrict__ on LDS params (round-6 lesson).
__device__ inline void stageW(const float4 v4[4], half8 (*hiA)[64], half8 (*loA)[64], int t)
{
    const int row = t >> 2, c0 = (t & 3) * 16;
    const float v[16] = {v4[0].x, v4[0].y, v4[0].z, v4[0].w, v4[1].x, v4[1].y, v4[1].z, v4[1].w,
                         v4[2].x, v4[2].y, v4[2].z, v4[2].w, v4[3].x, v4[3].y, v4[3].z, v4[3].w};
#pragma unroll
    for (int o = 0; o < 2; ++o) {
        const int cb     = c0 + o * 8;
        const int idx    = (row >> 4) * 2 + (cb >> 5);
        const int lane_s = (((cb >> 3) & 3) << 4) + (row & 15);
        half8 h, l;
#pragma unroll
        for (int j = 0; j < 8; ++j) {
            float f = v[o * 8 + j];
            _Float16 hi = (_Float16)f;
            h[j] = hi;
            l[j] = (_Float16)(f - (float)hi);
        }
        hiA[idx][lane_s] = h;
        loA[idx][lane_s] = l;
    }
}

// OCCUPANCY NOTE (R8-R11 measured): __launch_bounds__(256, N) clamps resident
// waves/EU to N on this toolchain (N=2 -> occupancy pinned ~19-24%; N=4 ->
// ~37-44%), i.e. the 2nd arg acts as min AND max. Use the explicit attribute
// instead: waves_per_eu(4,8) -> VGPR cap 512/4=128 (live ~90 fits, no spill)
// with residency allowed up to 8 waves/EU.
__global__ __launch_bounds__(256) __attribute__((amdgpu_waves_per_eu(4, 8)))
void pass1_kernel(const float* __restrict__ q, const float* __restrict__ kmat,
                  const int* __restrict__ labels, float* __restrict__ ws)
{
    __shared__ half8 khiF[8][64], kloF[8][64];   // 16 KB: frag-swizzled k (q in prologue)
    __shared__ float4 colred4[4][CHUNK];         // 4 KB (shuffle-reduced partials)
    __shared__ float nred[4][2];

    const int bidx = blockIdx.x;
    const int b    = bidx / (TILES * HALVES);
    const int rem  = bidx % (TILES * HALVES);
    const int tile = rem >> 1;
    const int half = rem & 1;
    const int chbase = half * CPB;
    const int tid  = threadIdx.x;
    const int lane = tid & 63;
    const int wave = tid >> 6;
    const int l15  = lane & 15;
    const int quad = lane >> 4;
    const int rowbase = tile * TILE_R;

    float* colmax_p = ws + WS_COLMAX;
    float* colsum_p = ws + WS_COLSUM;
    float* colssq_p = ws + WS_COLSSQ;
    float* colp1_p  = ws + WS_COLP1;
    float* rowmax_p = ws + WS_ROWMAX;
    float* rowsum_p = ws + WS_ROWSUM;
    float* rowssq_p = ws + WS_ROWSSQ;
    float* rowp2_p  = ws + WS_ROWP2;
    float* negs_p   = ws + WS_NEGS;
    float* negc_p   = ws + WS_NEGC;

    const float* kb = kmat + (size_t)b * S * C;
    const int*   lb = labels + ((size_t)b * L + rowbase) * S;

    // --- prologue: q -> frag-swizzled LDS -> A fragments in registers ---
    float4 tv[4];
    loadTile(q + ((size_t)b * L + rowbase) * C, tv, tid);
    stageW(tv, khiF, kloF, tid);
    // labels for first chunk: prefetch into registers
    int labn[16];
#pragma unroll
    for (int ct = 0; ct < 4; ++ct)
#pragma unroll
        for (int r = 0; r < 4; ++r)
            labn[ct * 4 + r] = lb[(size_t)(wave * 16 + quad * 4 + r) * S
                                  + chbase * CHUNK + ct * 16 + l15];
    __syncthreads();   // publish q staging before fragment reads
    half8 ah0 = khiF[wave * 2 + 0][lane], ah1 = khiF[wave * 2 + 1][lane];
    half8 al0 = kloF[wave * 2 + 0][lane], al1 = kloF[wave * 2 + 1][lane];
    // prefetch first k chunk into registers (khiF not overwritten until after S1)
    loadTile(kb + (size_t)chbase * CHUNK * C, tv, tid);

    float rmax[4], rsum[4], rssq[4], rp2[4];
#pragma unroll
    for (int i = 0; i < 4; ++i) { rmax[i] = -3.4e38f; rsum[i] = 0.f; rssq[i] = 0.f; rp2[i] = 0.f; }
    float negsum = 0.f;
    int   possum = 0;

    for (int c4 = 0; c4 < CPB; ++c4) {
        const int ch = chbase + c4;
        __syncthreads();   // S1: prev chunk's khiF frag reads + colred writes complete
        // combine + store column partials of previous chunk (reads colred4)
        if (c4 > 0 && tid < CHUNK) {
            float4 v = colred4[0][tid];
            float m0 = v.x, s1 = v.y, s2 = v.z, pp = v.w;
#pragma unroll
            for (int w = 1; w < 4; ++w) {
                float4 u = colred4[w][tid];
                m0 = fmaxf(m0, u.x); s1 += u.y; s2 += u.z; pp += u.w;
            }
            size_t idx = ((size_t)b * TILES + tile) * S + (ch - 1) * CHUNK + tid;
            colmax_p[idx] = m0; colsum_p[idx] = s1; colssq_p[idx] = s2; colp1_p[idx] = pp;
        }
        stageW(tv, khiF, kloF, tid);           // convert + write k(ch)
        if (c4 + 1 < CPB)
            loadTile(kb + (size_t)(ch + 1) * CHUNK * C, tv, tid);   // prefetch k(ch+1)
        __syncthreads();   // S2: k(ch) visible; colred4 reads done before re-write

        // current labels came from last iteration's prefetch; issue next prefetch
        int labv[16];
#pragma unroll
        for (int i = 0; i < 16; ++i) labv[i] = labn[i];
        if (c4 + 1 < CPB) {
#pragma unroll
            for (int ct = 0; ct < 4; ++ct)
#pragma unroll
                for (int r = 0; r < 4; ++r)
                    labn[ct * 4 + r] = lb[(size_t)(wave * 16 + quad * 4 + r) * S
                                          + (ch + 1) * CHUNK + ct * 16 + l15];
        }

        f32x4 acc[4];
#pragma unroll
        for (int ct = 0; ct < 4; ++ct) {
            half8 bh0 = khiF[ct * 2 + 0][lane], bh1 = khiF[ct * 2 + 1][lane];
            half8 bl0 = kloF[ct * 2 + 0][lane], bl1 = kloF[ct * 2 + 1][lane];
            f32x4 a = {0.f, 0.f, 0.f, 0.f};
            a = __builtin_amdgcn_mfma_f32_16x16x32_f16(ah0, bh0, a, 0, 0, 0);
            a = __builtin_amdgcn_mfma_f32_16x16x32_f16(ah0, bl0, a, 0, 0, 0);
            a = __builtin_amdgcn_mfma_f32_16x16x32_f16(al0, bh0, a, 0, 0, 0);
            a = __builtin_amdgcn_mfma_f32_16x16x32_f16(ah1, bh1, a, 0, 0, 0);
            a = __builtin_amdgcn_mfma_f32_16x16x32_f16(ah1, bl1, a, 0, 0, 0);
            a = __builtin_amdgcn_mfma_f32_16x16x32_f16(al1, bh1, a, 0, 0, 0);
            acc[ct] = a;
        }

        // epilogue: C/D layout col = l15, row = quad*4 + r  [m89-verified]
#pragma unroll
        for (int ct = 0; ct < 4; ++ct) {
            float cmax = -3.4e38f, csum = 0.f, cssq = 0.f, cp1 = 0.f;
#pragma unroll
            for (int r = 0; r < 4; ++r) {
                int lab = labv[ct * 4 + r];
                float sim = fmaf(0.5f, acc[ct][r], 0.5f);
                rmax[r] = fmaxf(rmax[r], sim);
                rsum[r] += sim;
                rssq[r] = fmaf(sim, sim, rssq[r]);
                cmax = fmaxf(cmax, sim);
                csum += sim;
                cssq = fmaf(sim, sim, cssq);
                float sc  = fminf(fmaxf(sim, EPSF), 1.f - EPSF);
                bool  isp = (lab == 1);
                float pos = isp ? 1.f : 0.f;
                float t   = isp ? sc : (1.f - sc);
                float nl  = -__logf(t);      // one log per element
                float pn  = pos * nl;
                rp2[r] += pn;
                cp1 += pn;
                negsum += nl - pn;           // adds nl only when neg
                possum += lab;               // negcnt derived at the end
            }
            // column reduce across quads (lanes sharing l15): xor 16, 32
#pragma unroll
            for (int m = 16; m <= 32; m <<= 1) {
                cmax = fmaxf(cmax, __shfl_xor(cmax, m, 64));
                csum += __shfl_xor(csum, m, 64);
                cssq += __shfl_xor(cssq, m, 64);
                cp1  += __shfl_xor(cp1,  m, 64);
            }
            if (lane < 16)
                colred4[wave][ct * 16 + l15] = make_float4(cmax, csum, cssq, cp1);
        }
    }

    __syncthreads();
    if (tid < CHUNK) {   // last chunk's column partials
        float4 v = colred4[0][tid];
        float m0 = v.x, s1 = v.y, s2 = v.z, pp = v.w;
#pragma unroll
        for (int w = 1; w < 4; ++w) {
            float4 u = colred4[w][tid];
            m0 = fmaxf(m0, u.x); s1 += u.y; s2 += u.z; pp += u.w;
        }
        size_t idx = ((size_t)b * TILES + tile) * S + (chbase + CPB - 1) * CHUNK + tid;
        colmax_p[idx] = m0; colsum_p[idx] = s1; colssq_p[idx] = s2; colp1_p[idx] = pp;
    }

    // row reduce across l15 (lanes sharing quad): xor 1,2,4,8 -> per-half partial
#pragma unroll
    for (int r = 0; r < 4; ++r) {
#pragma unroll
        for (int m = 1; m <= 8; m <<= 1) {
            rmax[r] = fmaxf(rmax[r], __shfl_xor(rmax[r], m, 64));
            rsum[r] += __shfl_xor(rsum[r], m, 64);
            rssq[r] += __shfl_xor(rssq[r], m, 64);
            rp2[r]  += __shfl_xor(rp2[r],  m, 64);
        }
    }
    if (l15 == 0) {
#pragma unroll
        for (int r = 0; r < 4; ++r) {
            size_t idx = ((size_t)b * L + rowbase + wave * 16 + quad * 4 + r) * HALVES + half;
            rowmax_p[idx] = rmax[r]; rowsum_p[idx] = rsum[r];
            rowssq_p[idx] = rssq[r]; rowp2_p[idx]  = rp2[r];
        }
    }

    // negatives: full block reduce (negcnt = elements - possum)
    float negcnt = (float)(16 * CPB - possum);
#pragma unroll
    for (int m = 1; m <= 32; m <<= 1) {
        negsum += __shfl_xor(negsum, m, 64);
        negcnt += __shfl_xor(negcnt, m, 64);
    }
    if (lane == 0) { nred[wave][0] = negsum; nred[wave][1] = negcnt; }
    __syncthreads();
    if (tid == 0) {
        float ns = 0.f, nc = 0.f;
        for (int w = 0; w < 4; ++w) { ns += nred[w][0]; nc += nred[w][1]; }
        negs_p[bidx] = ns; negc_p[bidx] = nc;
    }
}

template <bool MAX>
__device__ inline float bred(float v, float* red)
{
#pragma unroll
    for (int m = 1; m <= 32; m <<= 1) {
        float o = __shfl_xor(v, m, 64);
        v = MAX ? fmaxf(v, o) : (v + o);
    }
    const int wave = threadIdx.x >> 6;
    const int lane = threadIdx.x & 63;
    if (lane == 0) red[wave] = v;
    __syncthreads();
    if (threadIdx.x == 0) {
        float r = red[0];
        for (int w = 1; w < 8; ++w) r = MAX ? fmaxf(r, red[w]) : (r + red[w]);
        red[8] = r;
    }
    __syncthreads();
    float out = red[8];
    __syncthreads();   // protect red[] before next reduction reuses it
    return out;
}

// grid (B, 2): y==0 -> column path (sharp1 + loss1), y==1 -> row path (loss2 + loss3)
__global__ __launch_bounds__(512)
void pass2_kernel(const float* __restrict__ ws, float* __restrict__ out)
{
    __shared__ float red[9];
    const int b = blockIdx.x;
    const int s = threadIdx.x;

    if (blockIdx.y == 0) {
        const float* colmax_p = ws + WS_COLMAX;
        const float* colsum_p = ws + WS_COLSUM;
        const float* colssq_p = ws + WS_COLSSQ;
        const float* colp1_p  = ws + WS_COLP1;

        float m = -3.4e38f, sm = 0.f, sq = 0.f, p1 = 0.f;
#pragma unroll
        for (int t = 0; t < TILES; ++t) {
            size_t idx = ((size_t)b * TILES + t) * S + s;
            m = fmaxf(m, colmax_p[idx]);
            sm += colsum_p[idx];
            sq += colssq_p[idx];
            p1 += colp1_p[idx];
        }
        float mean  = sm * (1.f / L);
        float var   = (sq - sm * sm * (1.f / L)) * (1.f / (L - 1));
        float score = (m - mean) / sqrtf(var);

        float gmax = bred<true>(score, red);
        float e    = __expf(score - gmax);
        float esum = bred<false>(e, red);
        float sharp1 = e / esum;
        out[(size_t)b * S + s] = sharp1;
        float loss1 = bred<false>(sharp1 * p1, red);
        if (s == 0) atomicAdd(out + (size_t)B * S, loss1 * (0.5f / B));
    } else {
        const float* rowmax_p = ws + WS_ROWMAX;
        const float* rowsum_p = ws + WS_ROWSUM;
        const float* rowssq_p = ws + WS_ROWSSQ;
        const float* rowp2_p  = ws + WS_ROWP2;
        const float* negs_p   = ws + WS_NEGS;
        const float* negc_p   = ws + WS_NEGC;

        size_t ridx = ((size_t)b * L + s) * HALVES;
        float m2 = rowmax_p[ridx], sm2 = rowsum_p[ridx];
        float sq2 = rowssq_p[ridx], p2 = rowp2_p[ridx];
#pragma unroll
        for (int h = 1; h < HALVES; ++h) {
            m2 = fmaxf(m2, rowmax_p[ridx + h]);
            sm2 += rowsum_p[ridx + h];
            sq2 += rowssq_p[ridx + h];
            p2  += rowp2_p[ridx + h];
        }
        float mean2  = sm2 * (1.f / S);
        float var2   = (sq2 - sm2 * sm2 * (1.f / S)) * (1.f / (S - 1));
        float score2 = (m2 - mean2) / sqrtf(var2);

        float gmax2 = bred<true>(score2, red);
        float e2    = __expf(score2 - gmax2);
        float esum2 = bred<false>(e2, red);
        float loss2 = bred<false>((e2 / esum2) * p2, red);

        if (s == 0) {
            float ns = 0.f, nc = 0.f;
            for (int t = 0; t < TILES * HALVES; ++t) {
                ns += negs_p[b * TILES * HALVES + t];
                nc += negc_p[b * TILES * HALVES + t];
            }
            atomicAdd(out + (size_t)B * S, (0.5f * loss2 + ns / nc) * (1.f / B));
        }
    }
}

extern "C" void kernel_launch(void* const* d_in, const int* in_sizes, int n_in,
                              void* d_out, int out_size, void* d_ws, size_t ws_size,
                              hipStream_t stream)
{
    const float* q      = (const float*)d_in[0];
    const float* k      = (const float*)d_in[1];
    const int*   labels = (const int*)d_in[2];
    float* out = (float*)d_out;
    float* ws  = (float*)d_ws;

    // zero the scalar-loss slot (harness poisons d_out before timed replays)
    hipMemsetAsync((char*)d_out + (size_t)B * S * sizeof(float), 0, sizeof(float), stream);

    pass1_kernel<<<dim3(B * TILES * HALVES), dim3(256), 0, stream>>>(q, k, labels, ws);
    pass2_kernel<<<dim3(B, 2), dim3(512), 0, stream>>>(ws, out);
}

// Round 13
// 238.604 us; speedup vs baseline: 1.2764x; 1.2764x over previous
//
#include <hip/hip_runtime.h>

#define EPSF 1e-6f

typedef _Float16 half8 __attribute__((ext_vector_type(8)));
typedef float f32x4 __attribute__((ext_vector_type(4)));

constexpr int B = 128, L = 512, S = 512, C = 64;
constexpr int TILE_R = 64;            // rows per pass-1 block
constexpr int TILES  = L / TILE_R;    // 8
constexpr int CHUNK  = 64;            // cols per k-chunk
constexpr int NCHUNK = S / CHUNK;     // 8
constexpr int HALVES = 2;             // S-split: each block does NCHUNK/HALVES chunks
constexpr int CPB    = NCHUNK / HALVES;   // 4 chunks per block

// workspace float offsets (row stats are per-half partials)
constexpr size_t WS_COLMAX = 0;
constexpr size_t WS_COLSUM = WS_COLMAX + (size_t)B * TILES * S;
constexpr size_t WS_COLSSQ = WS_COLSUM + (size_t)B * TILES * S;
constexpr size_t WS_COLP1  = WS_COLSSQ + (size_t)B * TILES * S;
constexpr size_t WS_ROWMAX = WS_COLP1  + (size_t)B * TILES * S;
constexpr size_t WS_ROWSUM = WS_ROWMAX + (size_t)B * L * HALVES;
constexpr size_t WS_ROWSSQ = WS_ROWSUM + (size_t)B * L * HALVES;
constexpr size_t WS_ROWP2  = WS_ROWSSQ + (size_t)B * L * HALVES;
constexpr size_t WS_NEGS   = WS_ROWP2  + (size_t)B * L * HALVES;
constexpr size_t WS_NEGC   = WS_NEGS   + (size_t)B * TILES * HALVES;

// Load a thread's 16 consecutive floats of a 64x64 tile: row = t>>2, c0 = (t&3)*16.
__device__ inline void loadTile(const float* __restrict__ g, float4 v[4], int t)
{
    const float* src = g + (t >> 2) * 64 + (t & 3) * 16;
    v[0] = *(const float4*)(src);
    v[1] = *(const float4*)(src + 4);
    v[2] = *(const float4*)(src + 8);
    v[3] = *(const float4*)(src + 12);
}

// Write regs into frag-swizzled fp16 hi/lo LDS:
// arr[(row>>4)*2 + (c>>5)][(((c>>3)&3)<<4) + (row&15)][c&7] -> fragment read is
// one lane-linear ds_read_b128. No __restrict__ on LDS params (round-6 lesson).
__device__ inline void stageW(const float4 v4[4], half8 (*hiA)[64], half8 (*loA)[64], int t)
{
    const int row = t >> 2, c0 = (t & 3) * 16;
    const float v[16] = {v4[0].x, v4[0].y, v4[0].z, v4[0].w, v4[1].x, v4[1].y, v4[1].z, v4[1].w,
                         v4[2].x, v4[2].y, v4[2].z, v4[2].w, v4[3].x, v4[3].y, v4[3].z, v4[3].w};
#pragma unroll
    for (int o = 0; o < 2; ++o) {
        const int cb     = c0 + o * 8;
        const int idx    = (row >> 4) * 2 + (cb >> 5);
        const int lane_s = (((cb >> 3) & 3) << 4) + (row & 15);
        half8 h, l;
#pragma unroll
        for (int j = 0; j < 8; ++j) {
            float f = v[o * 8 + j];
            _Float16 hi = (_Float16)f;
            h[j] = hi;
            l[j] = (_Float16)(f - (float)hi);
        }
        hiA[idx][lane_s] = h;
        loA[idx][lane_s] = l;
    }
}

// REGISTER/OCCUPANCY MODEL (measured R8-R12): the allocator's VGPR cap is
// ~256/min_waves (launch_bounds arg2 or waves_per_eu min: 2->128, 4->64,
// 5->48), i.e. the effective per-SIMD VGPR pool is 256. Measured occupancy
// ~20% at VGPR 88 = floor(256/88) = 2 waves/SIMD -> the ceiling is the VGPR
// pool, not a launch_bounds clamp. Strategy: live set <= 85 regs -> 3
// waves/SIMD. waves_per_eu(3,8): cap floor(256/3)=85.
__global__ __launch_bounds__(256) __attribute__((amdgpu_waves_per_eu(3, 8)))
void pass1_kernel(const float* __restrict__ q, const float* __restrict__ kmat,
                  const int* __restrict__ labels, float* __restrict__ ws)
{
    __shared__ half8 khiF[8][64], kloF[8][64];   // 16 KB: frag-swizzled k (q in prologue)
    __shared__ float4 colred4[4][CHUNK];         // 4 KB (shuffle-reduced partials)
    __shared__ float nred[4][2];

    const int bidx = blockIdx.x;
    const int b    = bidx / (TILES * HALVES);
    const int rem  = bidx % (TILES * HALVES);
    const int tile = rem >> 1;
    const int half = rem & 1;
    const int chbase = half * CPB;
    const int tid  = threadIdx.x;
    const int lane = tid & 63;
    const int wave = tid >> 6;
    const int l15  = lane & 15;
    const int quad = lane >> 4;
    const int rowbase = tile * TILE_R;

    float* colmax_p = ws + WS_COLMAX;
    float* colsum_p = ws + WS_COLSUM;
    float* colssq_p = ws + WS_COLSSQ;
    float* colp1_p  = ws + WS_COLP1;
    float* rowmax_p = ws + WS_ROWMAX;
    float* rowsum_p = ws + WS_ROWSUM;
    float* rowssq_p = ws + WS_ROWSSQ;
    float* rowp2_p  = ws + WS_ROWP2;
    float* negs_p   = ws + WS_NEGS;
    float* negc_p   = ws + WS_NEGC;

    const float* kb = kmat + (size_t)b * S * C;
    const int*   lb = labels + ((size_t)b * L + rowbase) * S;

    // --- prologue: q -> frag-swizzled LDS -> A fragments in registers ---
    float4 tv[4];
    loadTile(q + ((size_t)b * L + rowbase) * C, tv, tid);
    stageW(tv, khiF, kloF, tid);
    // labels for first chunk (consumed in first epilogue; reloaded after each)
    int labn[16];
#pragma unroll
    for (int ct = 0; ct < 4; ++ct)
#pragma unroll
        for (int r = 0; r < 4; ++r)
            labn[ct * 4 + r] = lb[(size_t)(wave * 16 + quad * 4 + r) * S
                                  + chbase * CHUNK + ct * 16 + l15];
    __syncthreads();   // publish q staging before fragment reads
    half8 ah0 = khiF[wave * 2 + 0][lane], ah1 = khiF[wave * 2 + 1][lane];
    half8 al0 = kloF[wave * 2 + 0][lane], al1 = kloF[wave * 2 + 1][lane];
    // prefetch first k chunk into registers (khiF not overwritten until after S1)
    loadTile(kb + (size_t)chbase * CHUNK * C, tv, tid);

    float rmax[4], rsum[4], rssq[4], rp2[4];
#pragma unroll
    for (int i = 0; i < 4; ++i) { rmax[i] = -3.4e38f; rsum[i] = 0.f; rssq[i] = 0.f; rp2[i] = 0.f; }
    float negsum = 0.f;
    int   possum = 0;

    for (int c4 = 0; c4 < CPB; ++c4) {
        const int ch = chbase + c4;
        __syncthreads();   // S1: prev chunk's khiF frag reads + colred writes complete
        // combine + store column partials of previous chunk (reads colred4)
        if (c4 > 0 && tid < CHUNK) {
            float4 v = colred4[0][tid];
            float m0 = v.x, s1 = v.y, s2 = v.z, pp = v.w;
#pragma unroll
            for (int w = 1; w < 4; ++w) {
                float4 u = colred4[w][tid];
                m0 = fmaxf(m0, u.x); s1 += u.y; s2 += u.z; pp += u.w;
            }
            size_t idx = ((size_t)b * TILES + tile) * S + (ch - 1) * CHUNK + tid;
            colmax_p[idx] = m0; colsum_p[idx] = s1; colssq_p[idx] = s2; colp1_p[idx] = pp;
        }
        stageW(tv, khiF, kloF, tid);           // convert + write k(ch)
        if (c4 + 1 < CPB)
            loadTile(kb + (size_t)(ch + 1) * CHUNK * C, tv, tid);   // prefetch k(ch+1)
        __syncthreads();   // S2: k(ch) visible; colred4 reads done before re-write

        f32x4 acc[4];
#pragma unroll
        for (int ct = 0; ct < 4; ++ct) {
            half8 bh0 = khiF[ct * 2 + 0][lane], bh1 = khiF[ct * 2 + 1][lane];
            half8 bl0 = kloF[ct * 2 + 0][lane], bl1 = kloF[ct * 2 + 1][lane];
            f32x4 a = {0.f, 0.f, 0.f, 0.f};
            a = __builtin_amdgcn_mfma_f32_16x16x32_f16(ah0, bh0, a, 0, 0, 0);
            a = __builtin_amdgcn_mfma_f32_16x16x32_f16(ah0, bl0, a, 0, 0, 0);
            a = __builtin_amdgcn_mfma_f32_16x16x32_f16(al0, bh0, a, 0, 0, 0);
            a = __builtin_amdgcn_mfma_f32_16x16x32_f16(ah1, bh1, a, 0, 0, 0);
            a = __builtin_amdgcn_mfma_f32_16x16x32_f16(ah1, bl1, a, 0, 0, 0);
            a = __builtin_amdgcn_mfma_f32_16x16x32_f16(al1, bh1, a, 0, 0, 0);
            acc[ct] = a;
        }

        // epilogue: C/D layout col = l15, row = quad*4 + r  [m89-verified]
        // consumes labn loaded one chunk ahead (no labv copy -> ~16 fewer VGPRs)
#pragma unroll
        for (int ct = 0; ct < 4; ++ct) {
            float cmax = -3.4e38f, csum = 0.f, cssq = 0.f, cp1 = 0.f;
#pragma unroll
            for (int r = 0; r < 4; ++r) {
                int lab = labn[ct * 4 + r];
                float sim = fmaf(0.5f, acc[ct][r], 0.5f);
                rmax[r] = fmaxf(rmax[r], sim);
                rsum[r] += sim;
                rssq[r] = fmaf(sim, sim, rssq[r]);
                cmax = fmaxf(cmax, sim);
                csum += sim;
                cssq = fmaf(sim, sim, cssq);
                float sc  = fminf(fmaxf(sim, EPSF), 1.f - EPSF);
                bool  isp = (lab == 1);
                float pos = isp ? 1.f : 0.f;
                float t   = isp ? sc : (1.f - sc);
                float nl  = -__logf(t);      // one log per element
                float pn  = pos * nl;
                rp2[r] += pn;
                cp1 += pn;
                negsum += nl - pn;           // adds nl only when neg
                possum += lab;               // negcnt derived at the end
            }
            // column reduce across quads (lanes sharing l15): xor 16, 32
#pragma unroll
            for (int m = 16; m <= 32; m <<= 1) {
                cmax = fmaxf(cmax, __shfl_xor(cmax, m, 64));
                csum += __shfl_xor(csum, m, 64);
                cssq += __shfl_xor(cssq, m, 64);
                cp1  += __shfl_xor(cp1,  m, 64);
            }
            if (lane < 16)
                colred4[wave][ct * 16 + l15] = make_float4(cmax, csum, cssq, cp1);
        }

        // prefetch next chunk's labels AFTER consumption (cover: next S1/S2 +
        // staging + MFMA of chunk ch+1)
        if (c4 + 1 < CPB) {
#pragma unroll
            for (int ct = 0; ct < 4; ++ct)
#pragma unroll
                for (int r = 0; r < 4; ++r)
                    labn[ct * 4 + r] = lb[(size_t)(wave * 16 + quad * 4 + r) * S
                                          + (ch + 1) * CHUNK + ct * 16 + l15];
        }
    }

    __syncthreads();
    if (tid < CHUNK) {   // last chunk's column partials
        float4 v = colred4[0][tid];
        float m0 = v.x, s1 = v.y, s2 = v.z, pp = v.w;
#pragma unroll
        for (int w = 1; w < 4; ++w) {
            float4 u = colred4[w][tid];
            m0 = fmaxf(m0, u.x); s1 += u.y; s2 += u.z; pp += u.w;
        }
        size_t idx = ((size_t)b * TILES + tile) * S + (chbase + CPB - 1) * CHUNK + tid;
        colmax_p[idx] = m0; colsum_p[idx] = s1; colssq_p[idx] = s2; colp1_p[idx] = pp;
    }

    // row reduce across l15 (lanes sharing quad): xor 1,2,4,8 -> per-half partial
#pragma unroll
    for (int r = 0; r < 4; ++r) {
#pragma unroll
        for (int m = 1; m <= 8; m <<= 1) {
            rmax[r] = fmaxf(rmax[r], __shfl_xor(rmax[r], m, 64));
            rsum[r] += __shfl_xor(rsum[r], m, 64);
            rssq[r] += __shfl_xor(rssq[r], m, 64);
            rp2[r]  += __shfl_xor(rp2[r],  m, 64);
        }
    }
    if (l15 == 0) {
#pragma unroll
        for (int r = 0; r < 4; ++r) {
            size_t idx = ((size_t)b * L + rowbase + wave * 16 + quad * 4 + r) * HALVES + half;
            rowmax_p[idx] = rmax[r]; rowsum_p[idx] = rsum[r];
            rowssq_p[idx] = rssq[r]; rowp2_p[idx]  = rp2[r];
        }
    }

    // negatives: full block reduce (negcnt = elements - possum)
    float negcnt = (float)(16 * CPB - possum);
#pragma unroll
    for (int m = 1; m <= 32; m <<= 1) {
        negsum += __shfl_xor(negsum, m, 64);
        negcnt += __shfl_xor(negcnt, m, 64);
    }
    if (lane == 0) { nred[wave][0] = negsum; nred[wave][1] = negcnt; }
    __syncthreads();
    if (tid == 0) {
        float ns = 0.f, nc = 0.f;
        for (int w = 0; w < 4; ++w) { ns += nred[w][0]; nc += nred[w][1]; }
        negs_p[bidx] = ns; negc_p[bidx] = nc;
    }
}

template <bool MAX>
__device__ inline float bred(float v, float* red)
{
#pragma unroll
    for (int m = 1; m <= 32; m <<= 1) {
        float o = __shfl_xor(v, m, 64);
        v = MAX ? fmaxf(v, o) : (v + o);
    }
    const int wave = threadIdx.x >> 6;
    const int lane = threadIdx.x & 63;
    if (lane == 0) red[wave] = v;
    __syncthreads();
    if (threadIdx.x == 0) {
        float r = red[0];
        for (int w = 1; w < 8; ++w) r = MAX ? fmaxf(r, red[w]) : (r + red[w]);
        red[8] = r;
    }
    __syncthreads();
    float out = red[8];
    __syncthreads();   // protect red[] before next reduction reuses it
    return out;
}

// grid (B, 2): y==0 -> column path (sharp1 + loss1), y==1 -> row path (loss2 + loss3)
__global__ __launch_bounds__(512)
void pass2_kernel(const float* __restrict__ ws, float* __restrict__ out)
{
    __shared__ float red[9];
    const int b = blockIdx.x;
    const int s = threadIdx.x;

    if (blockIdx.y == 0) {
        const float* colmax_p = ws + WS_COLMAX;
        const float* colsum_p = ws + WS_COLSUM;
        const float* colssq_p = ws + WS_COLSSQ;
        const float* colp1_p  = ws + WS_COLP1;

        float m = -3.4e38f, sm = 0.f, sq = 0.f, p1 = 0.f;
#pragma unroll
        for (int t = 0; t < TILES; ++t) {
            size_t idx = ((size_t)b * TILES + t) * S + s;
            m = fmaxf(m, colmax_p[idx]);
            sm += colsum_p[idx];
            sq += colssq_p[idx];
            p1 += colp1_p[idx];
        }
        float mean  = sm * (1.f / L);
        float var   = (sq - sm * sm * (1.f / L)) * (1.f / (L - 1));
        float score = (m - mean) / sqrtf(var);

        float gmax = bred<true>(score, red);
        float e    = __expf(score - gmax);
        float esum = bred<false>(e, red);
        float sharp1 = e / esum;
        out[(size_t)b * S + s] = sharp1;
        float loss1 = bred<false>(sharp1 * p1, red);
        if (s == 0) atomicAdd(out + (size_t)B * S, loss1 * (0.5f / B));
    } else {
        const float* rowmax_p = ws + WS_ROWMAX;
        const float* rowsum_p = ws + WS_ROWSUM;
        const float* rowssq_p = ws + WS_ROWSSQ;
        const float* rowp2_p  = ws + WS_ROWP2;
        const float* negs_p   = ws + WS_NEGS;
        const float* negc_p   = ws + WS_NEGC;

        size_t ridx = ((size_t)b * L + s) * HALVES;
        float m2 = rowmax_p[ridx], sm2 = rowsum_p[ridx];
        float sq2 = rowssq_p[ridx], p2 = rowp2_p[ridx];
#pragma unroll
        for (int h = 1; h < HALVES; ++h) {
            m2 = fmaxf(m2, rowmax_p[ridx + h]);
            sm2 += rowsum_p[ridx + h];
            sq2 += rowssq_p[ridx + h];
            p2  += rowp2_p[ridx + h];
        }
        float mean2  = sm2 * (1.f / S);
        float var2   = (sq2 - sm2 * sm2 * (1.f / S)) * (1.f / (S - 1));
        float score2 = (m2 - mean2) / sqrtf(var2);

        float gmax2 = bred<true>(score2, red);
        float e2    = __expf(score2 - gmax2);
        float esum2 = bred<false>(e2, red);
        float loss2 = bred<false>((e2 / esum2) * p2, red);

        if (s == 0) {
            float ns = 0.f, nc = 0.f;
            for (int t = 0; t < TILES * HALVES; ++t) {
                ns += negs_p[b * TILES * HALVES + t];
                nc += negc_p[b * TILES * HALVES + t];
            }
            atomicAdd(out + (size_t)B * S, (0.5f * loss2 + ns / nc) * (1.f / B));
        }
    }
}

extern "C" void kernel_launch(void* const* d_in, const int* in_sizes, int n_in,
                              void* d_out, int out_size, void* d_ws, size_t ws_size,
                              hipStream_t stream)
{
    const float* q      = (const float*)d_in[0];
    const float* k      = (const float*)d_in[1];
    const int*   labels = (const int*)d_in[2];
    float* out = (float*)d_out;
    float* ws  = (float*)d_ws;

    // zero the scalar-loss slot (harness poisons d_out before timed replays)
    hipMemsetAsync((char*)d_out + (size_t)B * S * sizeof(float), 0, sizeof(float), stream);

    pass1_kernel<<<dim3(B * TILES * HALVES), dim3(256), 0, stream>>>(q, k, labels, ws);
    pass2_kernel<<<dim3(B, 2), dim3(512), 0, stream>>>(ws, out);
}